// Round 3
// baseline (502.581 us; speedup 1.0000x reference)
//
#include <hip/hip_runtime.h>

// GCN: 2-layer GraphConv, N=100000, E=1600000, 128 -> 128 -> 40 (fp32).
// Round 12: atomic CSR build (counting-sort pipeline deleted).
//   histconv: per-node degree via global atomics (+ coarse bucket hist bcntD,
//             LDS-aggregated) + x/W bf16 conversions.
//   scan:     196 blocks: bcntD self-scan -> bucket base; LDS scan of 512
//             indeg -> row_ptr/cur/dstn/srcn.
//   scatter:  1 edge/thread: pos = atomicAdd(cur[dst]); esrc[pos] = src.
//   fused:    gather1+GEMM1+GEMM2 (unchanged from Round 11).
//   gather2:  unchanged.
constexpr int NN   = 100000;
constexpr int NE   = 1600000;
constexpr int INF  = 128;
constexpr int NC   = 40;

constexpr int BKSH = 9;                        // 512 nodes per coarse bucket
constexpr int NBK  = (NN + 511) / 512;         // 196 buckets
constexpr int HB   = 391;                      // hist blocks in merged kernel

typedef __attribute__((ext_vector_type(8))) short short8;
typedef __attribute__((ext_vector_type(4))) float f32x4;

__device__ __forceinline__ float bflo(unsigned int u) { return __uint_as_float(u << 16); }
__device__ __forceinline__ float bfhi(unsigned int u) { return __uint_as_float(u & 0xffff0000u); }
__device__ __forceinline__ unsigned short f2bf(float f) {          // RNE
    unsigned int u = __float_as_uint(f);
    return (unsigned short)((u + 0x7fffu + ((u >> 16) & 1u)) >> 16);
}
__device__ __forceinline__ unsigned int pack2(float a, float b) {
    return (unsigned int)f2bf(a) | ((unsigned int)f2bf(b) << 16);
}

// blocks 0..HB-1: per-node degrees (global atomics) + coarse dst-bucket hist.
// blocks HB..HB+6249: x (fp32) -> xh (bf16). +2 blocks: W1/W2 transpose->bf16.
__global__ __launch_bounds__(256) void histconv_kernel(const int* __restrict__ src,
                                                       const int* __restrict__ dst,
                                                       int* __restrict__ indeg,
                                                       int* __restrict__ outdeg,
                                                       unsigned int* __restrict__ bcntD,
                                                       const float* __restrict__ x,
                                                       const float* __restrict__ W1,
                                                       const float* __restrict__ W2,
                                                       unsigned short* __restrict__ xh,
                                                       unsigned short* __restrict__ w1t,
                                                       unsigned short* __restrict__ w2t) {
    const int b = blockIdx.x;
    const int tid = threadIdx.x;
    if (b < HB) {
        __shared__ unsigned int hcD[NBK];
        for (int i = tid; i < NBK; i += 256) hcD[i] = 0u;
        __syncthreads();
        int gid = b * 256 + tid;
        int stride = HB * 256;
        for (int e = gid; e < NE; e += stride) {
            int d = dst[e];
            int s = src[e];
            atomicAdd(&indeg[d], 1);
            atomicAdd(&outdeg[s], 1);
            atomicAdd(&hcD[d >> BKSH], 1u);
        }
        __syncthreads();
        for (int i = tid; i < NBK; i += 256)
            if (hcD[i]) atomicAdd(&bcntD[i], hcD[i]);
    } else if (b < HB + 6250) {
        int j = (b - HB) * 256 + tid;                // uint4 index, N*128/8 = 1.6M
        float4 v0 = ((const float4*)x)[2 * j];
        float4 v1 = ((const float4*)x)[2 * j + 1];
        uint4 o;
        o.x = pack2(v0.x, v0.y);
        o.y = pack2(v0.z, v0.w);
        o.z = pack2(v1.x, v1.y);
        o.w = pack2(v1.z, v1.w);
        ((uint4*)xh)[j] = o;
    } else if (b == HB + 6250) {
        for (int i = tid; i < 128 * 128; i += 256) {
            int k = i >> 7, n = i & 127;
            w1t[n * 128 + k] = f2bf(W1[i]);
        }
    } else {
        for (int i = tid; i < 48 * 128; i += 256) {
            int n = i >> 7, k = i & 127;
            w2t[i] = f2bf((n < NC) ? W2[k * NC + n] : 0.f);
        }
    }
}

// 196 blocks x 512: bucket base via bcntD self-scan, then LDS scan of the
// bucket's 512 in-degrees -> row_ptr, cur (scatter cursor), dstn, srcn.
__global__ __launch_bounds__(512) void scan_kernel(const unsigned int* __restrict__ bcntD,
                                                   const int* __restrict__ indeg,
                                                   const int* __restrict__ outdeg,
                                                   int* __restrict__ row_ptr,
                                                   int* __restrict__ cur,
                                                   float* __restrict__ dstn,
                                                   float* __restrict__ srcn) {
    __shared__ int sc[512];
    __shared__ int base_s;
    const int tid = threadIdx.x;
    const int b = blockIdx.x;

    // exclusive scan of bucket counts -> this bucket's base
    {
        int v = (tid < NBK) ? (int)bcntD[tid] : 0;
        sc[tid] = v;
        __syncthreads();
        for (int off = 1; off < 512; off <<= 1) {
            int t = (tid >= off) ? sc[tid - off] : 0;
            __syncthreads();
            sc[tid] += t;
            __syncthreads();
        }
        if (tid == b) base_s = sc[b] - v;
        __syncthreads();
    }
    const int base = base_s;
    const int n0 = b << BKSH;
    const int nloc = min(512, NN - n0);

    int deg = 0, odeg = 0;
    if (tid < nloc) {
        deg = indeg[n0 + tid];
        odeg = outdeg[n0 + tid];
    }
    sc[tid] = deg;
    __syncthreads();
    for (int off = 1; off < 512; off <<= 1) {
        int t = (tid >= off) ? sc[tid - off] : 0;
        __syncthreads();
        sc[tid] += t;
        __syncthreads();
    }
    if (tid < nloc) {
        int g = n0 + tid;
        int excl = sc[tid] - deg;
        row_ptr[g] = base + excl;
        cur[g] = base + excl;
        dstn[g] = rsqrtf(fmaxf((float)deg, 1.0f));    // dst_norm (in-degree)
        srcn[g] = rsqrtf(fmaxf((float)odeg, 1.0f));   // src_norm (out-degree)
    }
    if (b == NBK - 1 && tid == 0) row_ptr[NN] = NE;
}

// 1 edge/thread: CSR fill via fetch-add on per-node cursors (L2-resident).
__global__ __launch_bounds__(256) void scatter_kernel(const int* __restrict__ src,
                                                      const int* __restrict__ dst,
                                                      int* __restrict__ cur,
                                                      int* __restrict__ esrc) {
    int e = blockIdx.x * 256 + threadIdx.x;
    if (e >= NE) return;
    int d = dst[e];
    int s = src[e];
    int pos = atomicAdd(&cur[d], 1);
    esrc[pos] = s;
}

// Fused gather1 + GEMM1 + GEMM2. 64 nodes/block, 4 waves, wave-private 16 rows.
// Phase 1: per wave, 16 nodes sequentially; predicated 24-edge batches
//   (quad group owns edge slot t*4+quad, l16 reads uint4 of the 256 B row);
//   shfl-reduce over quads; lanes<16 write the bf16 row into the wave's own
//   At rows (no cross-wave LDS traffic -> single barrier for dn/sn/b1 only).
// Phase 2: MFMA 16x16x32 bf16. A-frags from At (own rows); B-frags straight
//   from global w1t/w2t (L1-resident, shared across all blocks). h = relu(
//   dstn*(agg@W1)+b1) -> back into At; out = (h@W2)*srcn -> hwb (bf16, 40c).
__global__ __launch_bounds__(256) void fused_kernel(const int* __restrict__ row_ptr,
                                                    const int* __restrict__ esrc,
                                                    const unsigned short* __restrict__ xh,
                                                    const float* __restrict__ srcn,
                                                    const unsigned short* __restrict__ w1t,
                                                    const unsigned short* __restrict__ w2t,
                                                    const float* __restrict__ b1,
                                                    const float* __restrict__ dstn,
                                                    unsigned short* __restrict__ hwb) {
    __shared__ unsigned short At[64 * 128];    // 16 KB: agg tile, then h tile
    __shared__ float dn[64], sn[64], b1l[128];
    const int tid  = threadIdx.x;
    const int r0   = blockIdx.x * 64;
    const int wv   = tid >> 6;
    const int lane = tid & 63;

    if (tid < 64) {
        int r = r0 + tid;
        dn[tid] = (r < NN) ? dstn[r] : 0.f;
        sn[tid] = (r < NN) ? srcn[r] : 0.f;
    }
    if (tid >= 64 && tid < 192) b1l[tid - 64] = b1[tid - 64];
    __syncthreads();

    // ---- phase 1: gather 16 nodes into wave-private At rows ----
    const int quad = lane >> 4;       // edge-slot group 0..3
    const int l16  = lane & 15;       // uint4 index within 256 B row
    for (int i = 0; i < 16; ++i) {
        const int node = r0 + wv * 16 + i;
        float a0 = 0.f, a1 = 0.f, a2 = 0.f, a3 = 0.f;
        float a4 = 0.f, a5 = 0.f, a6 = 0.f, a7 = 0.f;
        if (node < NN) {
            int beg = __builtin_amdgcn_readfirstlane(row_ptr[node]);
            int end = __builtin_amdgcn_readfirstlane(row_ptr[node + 1]);
            for (int e = beg; e < end; e += 24) {
                const int rem = end - e;
                int s[6];
#pragma unroll
                for (int t = 0; t < 6; ++t) {
                    int slot = t * 4 + quad;
                    s[t] = esrc[(slot < rem) ? (e + slot) : beg];
                }
                float n[6];
                uint4 u[6];
#pragma unroll
                for (int t = 0; t < 6; ++t) {
                    int slot = t * 4 + quad;
                    n[t] = (slot < rem) ? srcn[s[t]] : 0.f;
                    u[t] = ((const uint4*)(xh + (size_t)s[t] * INF))[l16];
                }
#pragma unroll
                for (int t = 0; t < 6; ++t) {
                    a0 += bflo(u[t].x) * n[t];
                    a1 += bfhi(u[t].x) * n[t];
                    a2 += bflo(u[t].y) * n[t];
                    a3 += bfhi(u[t].y) * n[t];
                    a4 += bflo(u[t].z) * n[t];
                    a5 += bfhi(u[t].z) * n[t];
                    a6 += bflo(u[t].w) * n[t];
                    a7 += bfhi(u[t].w) * n[t];
                }
            }
        }
        a0 += __shfl_down(a0, 32); a1 += __shfl_down(a1, 32);
        a2 += __shfl_down(a2, 32); a3 += __shfl_down(a3, 32);
        a4 += __shfl_down(a4, 32); a5 += __shfl_down(a5, 32);
        a6 += __shfl_down(a6, 32); a7 += __shfl_down(a7, 32);
        a0 += __shfl_down(a0, 16); a1 += __shfl_down(a1, 16);
        a2 += __shfl_down(a2, 16); a3 += __shfl_down(a3, 16);
        a4 += __shfl_down(a4, 16); a5 += __shfl_down(a5, 16);
        a6 += __shfl_down(a6, 16); a7 += __shfl_down(a7, 16);
        if (lane < 16) {
            uint4 o;
            o.x = pack2(a0, a1);
            o.y = pack2(a2, a3);
            o.z = pack2(a4, a5);
            o.w = pack2(a6, a7);
            *(uint4*)&At[(wv * 16 + i) * 128 + l16 * 8] = o;
        }
    }
    // no barrier: each wave reads only its own 16 rows below

    // ---- phase 2: MFMA GEMM1 (+relu) and GEMM2 ----
    const int lrow  = lane & 15;
    const int lquad = lane >> 4;

    short8 afrag[4];
#pragma unroll
    for (int ks = 0; ks < 4; ++ks)
        afrag[ks] = *(const short8*)&At[(wv * 16 + lrow) * 128 + ks * 32 + lquad * 8];
    float hreg[8][4];
#pragma unroll
    for (int nt = 0; nt < 8; ++nt) {
        f32x4 acc = {0.f, 0.f, 0.f, 0.f};
#pragma unroll
        for (int ks = 0; ks < 4; ++ks) {
            short8 bfr = *(const short8*)&w1t[(nt * 16 + lrow) * 128 + ks * 32 + lquad * 8];
            acc = __builtin_amdgcn_mfma_f32_16x16x32_bf16(afrag[ks], bfr, acc, 0, 0, 0);
        }
#pragma unroll
        for (int i = 0; i < 4; ++i) hreg[nt][i] = acc[i];
    }
#pragma unroll
    for (int nt = 0; nt < 8; ++nt) {
        int col = nt * 16 + lrow;
        float bb = b1l[col];
#pragma unroll
        for (int i = 0; i < 4; ++i) {
            int row = wv * 16 + lquad * 4 + i;
            At[row * 128 + col] = f2bf(fmaxf(hreg[nt][i] * dn[row] + bb, 0.f));
        }
    }
    // still wave-private (each wave reads back only its own rows)

#pragma unroll
    for (int ks = 0; ks < 4; ++ks)
        afrag[ks] = *(const short8*)&At[(wv * 16 + lrow) * 128 + ks * 32 + lquad * 8];
#pragma unroll
    for (int nt = 0; nt < 3; ++nt) {
        f32x4 acc = {0.f, 0.f, 0.f, 0.f};
#pragma unroll
        for (int ks = 0; ks < 4; ++ks) {
            short8 bfr = *(const short8*)&w2t[(nt * 16 + lrow) * 128 + ks * 32 + lquad * 8];
            acc = __builtin_amdgcn_mfma_f32_16x16x32_bf16(afrag[ks], bfr, acc, 0, 0, 0);
        }
        int col = nt * 16 + lrow;
        if (col < NC) {
#pragma unroll
            for (int i = 0; i < 4; ++i) {
                int row = wv * 16 + lquad * 4 + i;
                int grow = r0 + row;
                if (grow < NN)
                    hwb[(size_t)grow * NC + col] = f2bf(acc[i] * sn[row]);
            }
        }
    }
}

// one wave per node. lane = g*10+j (g<6, j<10): 6 edge slots, each edge's
// 80 B row read by 10 lanes as uint2 (4 bf16). Predicated 18-edge batches
// (3 independent loads per lane in flight); invalid slots clamp to edge `beg`
// with multiplicative zero mask. fp32 acc; shfl reduce into lanes 0..9,
// which store float4 with fused *dstn + b2.
__global__ __launch_bounds__(256) void gather2_kernel(const int* __restrict__ row_ptr,
                                                      const int* __restrict__ esrc,
                                                      const unsigned short* __restrict__ hwb,
                                                      const float* __restrict__ dst_norm,
                                                      const float* __restrict__ b2,
                                                      float* __restrict__ out) {
    int node = (blockIdx.x * blockDim.x + threadIdx.x) >> 6;
    int lane = threadIdx.x & 63;
    if (node >= NN) return;
    int beg = __builtin_amdgcn_readfirstlane(row_ptr[node]);
    int end = __builtin_amdgcn_readfirstlane(row_ptr[node + 1]);
    const int g = lane / 10;          // edge slot 0..5 (g==6: lanes 60-63 masked)
    const int j = lane - g * 10;      // uint2 index within 80 B row
    const bool active = (g < 6);
    float4 acc = make_float4(0.f, 0.f, 0.f, 0.f);
    for (int e = beg; e < end; e += 18) {
        const int rem = end - e;
        int s[3];
        float m[3];
#pragma unroll
        for (int q = 0; q < 3; ++q) {
            int slot = q * 6 + g;
            bool v = active && (slot < rem);
            int idx = v ? (e + slot) : beg;
            s[q] = esrc[idx];
            m[q] = v ? 1.f : 0.f;
        }
        uint2 u[3];
#pragma unroll
        for (int q = 0; q < 3; ++q)
            u[q] = ((const uint2*)(hwb + (size_t)s[q] * NC))[j];
#pragma unroll
        for (int q = 0; q < 3; ++q) {
            acc.x += bflo(u[q].x) * m[q];
            acc.y += bfhi(u[q].x) * m[q];
            acc.z += bflo(u[q].y) * m[q];
            acc.w += bfhi(u[q].y) * m[q];
        }
    }
    float4 tot = acc;
#pragma unroll
    for (int k = 1; k < 6; ++k) {
        tot.x += __shfl(acc.x, j + 10 * k);
        tot.y += __shfl(acc.y, j + 10 * k);
        tot.z += __shfl(acc.z, j + 10 * k);
        tot.w += __shfl(acc.w, j + 10 * k);
    }
    if (lane < 10) {
        float dnv = dst_norm[node];
        float4 bb = ((const float4*)b2)[j];
        float4 o;
        o.x = tot.x * dnv + bb.x;
        o.y = tot.y * dnv + bb.y;
        o.z = tot.z * dnv + bb.z;
        o.w = tot.w * dnv + bb.w;
        ((float4*)(out + (size_t)node * NC))[j] = o;
    }
}

extern "C" void kernel_launch(void* const* d_in, const int* in_sizes, int n_in,
                              void* d_out, int out_size, void* d_ws, size_t ws_size,
                              hipStream_t stream) {
    const float* x   = (const float*)d_in[0];
    const float* W1  = (const float*)d_in[1];
    const float* b1  = (const float*)d_in[2];
    const float* W2  = (const float*)d_in[3];
    const float* b2  = (const float*)d_in[4];
    const int*   src = (const int*)d_in[5];
    const int*   dst = (const int*)d_in[6];
    float* out = (float*)d_out;

    // workspace (4B units):
    // indeg[NN] | outdeg[NN] | bcntD[256] | row_ptr[NN+1] | cur[NN] |
    // dstn[NN] | srcn[NN] | esrc[NE] | pad | xh[NN*64] | w1t | w2t | hwb[NN*20]
    int* indeg  = (int*)d_ws;
    int* outdeg = indeg + NN;
    unsigned int* bcntD = (unsigned int*)(outdeg + NN);
    int* row_ptr = (int*)(bcntD + 256);
    int* cur     = row_ptr + NN + 1;
    float* dstn  = (float*)(cur + NN);
    float* srcn  = dstn + NN;
    int* esrc    = (int*)(srcn + NN);
    size_t ofs = (size_t)(2 * NN + 256) + (NN + 1) + 3 * (size_t)NN + NE;
    ofs = (ofs + 3) & ~(size_t)3;                 // 16B align
    unsigned short* xh   = (unsigned short*)((float*)d_ws + ofs);
    unsigned short* w1t  = xh + (size_t)NN * INF;
    unsigned short* w2t  = w1t + 128 * 128;
    unsigned short* hwb  = w2t + 48 * 128;

    // zero: indeg | outdeg | bcntD (contiguous)
    hipMemsetAsync(indeg, 0, (size_t)(2 * NN + 256) * sizeof(int), stream);

    histconv_kernel<<<HB + 6252, 256, 0, stream>>>(src, dst, indeg, outdeg, bcntD,
                                                   x, W1, W2, xh, w1t, w2t);
    scan_kernel<<<NBK, 512, 0, stream>>>(bcntD, indeg, outdeg,
                                         row_ptr, cur, dstn, srcn);
    scatter_kernel<<<(NE + 255) / 256, 256, 0, stream>>>(src, dst, cur, esrc);
    fused_kernel<<<(NN + 63) / 64, 256, 0, stream>>>(row_ptr, esrc, xh, srcn,
                                                     w1t, w2t, b1, dstn, hwb);
    gather2_kernel<<<(NN * 64 + 255) / 256, 256, 0, stream>>>(row_ptr, esrc, hwb,
                                                              dstn, b2, out);
}